// Round 19
// baseline (199.606 us; speedup 1.0000x reference)
//
#include <hip/hip_runtime.h>
#include <hip/hip_bf16.h>
#include <math.h>

#define DM 768
#define HEADS 12
#define BQ 2
#define TQ 2048
#define TK 4096
#define NSPLIT 4
#define KTS (TK / 64 / NSPLIT)          // K-tiles per split = 16
#define ROWS (BQ * HEADS * TQ)          // 49152 q-rows total

typedef __attribute__((ext_vector_type(8))) short bf16x8;   // 8 bf16 (4 VGPRs) MFMA frag
typedef __attribute__((ext_vector_type(4))) float f32x4;    // 16x16 MFMA accum
typedef __attribute__((ext_vector_type(16))) float f32x16;  // 32x32 MFMA accum
typedef __attribute__((ext_vector_type(4))) short short4v;  // 8B vector
typedef __attribute__((ext_vector_type(2))) unsigned uint2v; // 8B vector

// packed 2x f32 -> 1x u32 (2 bf16, lo = first arg); v_cvt_pk_bf16_f32
__device__ inline unsigned pk2bf(float a, float b) {
    union { __hip_bfloat162 h; unsigned u; } c;
    c.h = __float22bfloat162_rn(make_float2(a, b));
    return c.u;
}
// single f32->bf16 RNE in ONE instruction (cvt_pk with dup, take low half)
__device__ inline short f2bf(float f) { return (short)(pk2bf(f, f) & 0xffffu); }

__device__ inline float bf2f(short s) {
    union { unsigned u; float f; } a; a.u = ((unsigned)(unsigned short)s) << 16;
    return a.f;
}

// v_permlane32_swap_b32 builtin (compiler owns hazard wait-states).
__device__ inline void plswap(unsigned &a, unsigned &b) {
    uint2v r = __builtin_amdgcn_permlane32_swap(a, b, false, false);
    a = r[0]; b = r[1];
}
__device__ inline void plswap2(unsigned &a, unsigned &b, unsigned x) {
    uint2v r = __builtin_amdgcn_permlane32_swap(x, x, false, false);
    a = r[0]; b = r[1];
}

// async global->LDS DMA, 16B per lane. LDS dest = wave-uniform base + lane*16;
// global src is PER-LANE (guide §5: pre-swizzled-source pattern, rule #21).
__device__ inline void glds16(const void* g, void* l) {
    __builtin_amdgcn_global_load_lds(
        (const __attribute__((address_space(1))) unsigned*)g,
        (__attribute__((address_space(3))) unsigned*)l, 16, 0, 0);
}

// ---------------------------------------------------------------------------
// RoPE table, packed float2 {su, cu} per (t, u). fp64 (matches np float64 ref).
// ---------------------------------------------------------------------------
__global__ void rope_tables(float2* scu) {
    int idx = blockIdx.x * 256 + threadIdx.x;
    if (idx >= TK * 32) return;
    int t = idx >> 5, j = idx & 31;
    double su, cu;
    if (j < 16) {
        su = sin((double)t * pow(10000.0, -(double)(2 * (2 * j)) / 64.0));
        cu = sin((double)t * pow(10000.0, -(double)(2 * (2 * j + 1)) / 64.0));
    } else {
        su = cos((double)t * pow(10000.0, -(double)(2 * (2 * j - 32)) / 64.0));
        cu = cos((double)t * pow(10000.0, -(double)(2 * (2 * j - 31)) / 64.0));
    }
    scu[idx] = make_float2((float)su, (float)cu);
}

// ---------------------------------------------------------------------------
// Fused QKV projection + RoPE (Q,K) / transpose (V) epilogue.
// R19: A operand staged via global_load_lds DMA (fp32, double-buffered LDS,
// 32B-granule XOR swizzle folded into the per-lane DMA SOURCE address;
// linear DMA dest; swizzled ds_read + cvt_pk at fragment read). B path
// unchanged (reg-staged fp32->bf16, 72-pad). DMA for step k+1 issues into
// Af[cur^1] after bar1(k); the compiler's conservative vmcnt-drain before
// each s_barrier provides all synchronization (m97 structure).
// Tile 64x128, 4 waves of 32x64, XCD-pinned 1920-block grid (R18 geometry).
// ---------------------------------------------------------------------------
__global__ __launch_bounds__(256) void gemm_qkv(
        const float* __restrict__ query, const float* __restrict__ key_,
        const float* __restrict__ value,
        const float* __restrict__ Wq, const float* __restrict__ bq,
        const float* __restrict__ Wk, const float* __restrict__ bk,
        const float* __restrict__ Wv, const float* __restrict__ bv,
        const float2* __restrict__ scu,
        short* __restrict__ qh, short* __restrict__ kh, short* __restrict__ vt,
        float qscale) {
    __shared__ float Af[2][64 * 64];    // 2 x 16 KB, LINEAR (DMA dest)
    __shared__ short Blds[128 * 72];    // 18.4 KB, reg-staged + padded
    const int tid = threadIdx.x;
    const int lane = tid & 63, wid = tid >> 6;
    const int wr = wid >> 1, wc = wid & 1;      // 2 M-halves x 2 N-halves
    const int l4 = lane >> 4, l15 = lane & 15;
    // XCD-pinned decode: 1920 blocks = 8 XCDs x (40 bx x 6 bn)
    const int id = blockIdx.x;
    const int xcd = id & 7, pos = id >> 3;
    const int bx = xcd * 40 + pos / 6;
    const int bn = (pos % 6) * 128;

    const float* X; const float* W; const float* bias;
    short* dst; int bm, tsh, mode; float scale;
    if (bx < 64)       { X = query; W = Wq; bias = bq; dst = qh; bm = bx * 64;         tsh = 11; mode = 0; scale = qscale; }
    else if (bx < 192) { X = key_;  W = Wk; bias = bk; dst = kh; bm = (bx - 64) * 64;  tsh = 12; mode = 0; scale = 1.f; }
    else               { X = value; W = Wv; bias = bv; dst = vt; bm = (bx - 192) * 64; tsh = 12; mode = 1; scale = 1.f; }
    const int T = 1 << tsh, tmask = T - 1;

    const float* Xb = X + (size_t)bm * DM;
    const float* Wb = W + (size_t)bn * DM;

    // ---- A DMA addressing: 16 chunks of 1KB; wave w does chunks w*4..w*4+3.
    // Lane's 16B unit: off16 = cc*64 + lane -> row r = off16>>4, unit u = off16&15,
    // 32B granule g2 = u>>1, half h = u&1. Source granule is XOR-swizzled by r&7.
    const char* XbB = (const char*)Xb;
    size_t srcA[4];
#pragma unroll
    for (int q = 0; q < 4; ++q) {
        int off16 = (wid * 4 + q) * 64 + lane;
        int r = off16 >> 4, u = off16 & 15;
        int g2 = u >> 1, h = u & 1;
        srcA[q] = (size_t)r * DM * 4 + (size_t)(((g2 ^ (r & 7)) << 5) + (h << 4));
    }
    // ---- A fragment read offsets (f32 elems): row*64 + swizzled-granule*8
    const int rg = l15 & 7;
    int aoff[2][2];   // [i][kk]
#pragma unroll
    for (int i = 0; i < 2; ++i)
#pragma unroll
        for (int kk = 0; kk < 2; ++kk)
            aoff[i][kk] = (wr * 32 + i * 16 + l15) * 64 + (((kk * 4 + l4) ^ rg) << 3);

    // ---- B staging (unchanged): 128 rows x 64 f32 -> 8 float4/thread
    int srB[8], skB[8];
#pragma unroll
    for (int p = 0; p < 8; ++p) {
        int c = p * 256 + tid;
        srB[p] = c >> 4; skB[p] = (c & 15) * 4;
    }

    f32x4 acc[2][4] = {};
    float4 fw[8];

    // prologue: DMA A(k=0) -> Af[0]; W(k=0) -> regs
#pragma unroll
    for (int q = 0; q < 4; ++q)
        glds16(XbB + srcA[q], &Af[0][(wid * 4 + q) * 256]);
#pragma unroll
    for (int p = 0; p < 8; ++p)
        fw[p] = *reinterpret_cast<const float4*>(&Wb[(size_t)srB[p] * DM + skB[p]]);

    int cur = 0;
    for (int k0 = 0; k0 < DM; k0 += 64) {
        // B: staged regs -> LDS (guarded by bar2 of previous step)
#pragma unroll
        for (int p = 0; p < 8; ++p) {
            uint2v t4; t4.x = pk2bf(fw[p].x, fw[p].y); t4.y = pk2bf(fw[p].z, fw[p].w);
            *reinterpret_cast<uint2v*>(&Blds[srB[p] * 72 + skB[p]]) = t4;
        }
        __syncthreads();    // bar1: B(k) visible; drains DMA -> Af[cur] ready

        // issue NEXT step's A-DMA (into the idle buffer) and W loads
        if (k0 + 64 < DM) {
#pragma unroll
            for (int q = 0; q < 4; ++q)
                glds16(XbB + (size_t)(k0 + 64) * 4 + srcA[q],
                       &Af[cur ^ 1][(wid * 4 + q) * 256]);
#pragma unroll
            for (int p = 0; p < 8; ++p)
                fw[p] = *reinterpret_cast<const float4*>(&Wb[(size_t)srB[p] * DM + k0 + 64 + skB[p]]);
        }

        // compute: 2 sub-K of 32, A from f32 LDS (cvt at read), B from Blds
#pragma unroll
        for (int kk = 0; kk < 2; ++kk) {
            bf16x8 af[2], bfr[4];
#pragma unroll
            for (int i = 0; i < 2; ++i) {
                const float* ap = &Af[cur][aoff[i][kk]];
                float4 x0 = *reinterpret_cast<const float4*>(ap);
                float4 x1 = *reinterpret_cast<const float4*>(ap + 4);
                union { unsigned u[4]; bf16x8 v; } cc;
                cc.u[0] = pk2bf(x0.x, x0.y); cc.u[1] = pk2bf(x0.z, x0.w);
                cc.u[2] = pk2bf(x1.x, x1.y); cc.u[3] = pk2bf(x1.z, x1.w);
                af[i] = cc.v;
            }
#pragma unroll
            for (int j = 0; j < 4; ++j)
                bfr[j] = *reinterpret_cast<const bf16x8*>(&Blds[(wc * 64 + j * 16 + l15) * 72 + kk * 32 + l4 * 8]);
            __builtin_amdgcn_s_setprio(1);
#pragma unroll
            for (int i = 0; i < 2; ++i)
#pragma unroll
                for (int j = 0; j < 4; ++j)
                    acc[i][j] = __builtin_amdgcn_mfma_f32_16x16x32_bf16(af[i], bfr[j], acc[i][j], 0, 0, 0);
            __builtin_amdgcn_s_setprio(0);
        }
        __syncthreads();    // bar2: LDS reads done; (drains next-step DMA partially)
        cur ^= 1;
    }

    if (mode == 0) {
#pragma unroll
        for (int i = 0; i < 2; ++i) {
            int mrow0 = bm + wr * 32 + i * 16 + l4 * 4;
#pragma unroll
            for (int j = 0; j < 4; ++j) {
                int n = bn + wc * 64 + j * 16 + l15;
                int hh = n >> 6, c = n & 63, u = c >> 1, odd = c & 1;
                float bb = bias[n];
#pragma unroll
                for (int r = 0; r < 4; ++r) {
                    float val = acc[i][j][r] + bb;
                    float pv = __shfl_xor(val, 1);
                    int mrow = mrow0 + r;
                    int b_ = mrow >> tsh, t = mrow & tmask;
                    float2 sc = scu[t * 32 + u];
                    float outv = odd ? (pv * sc.x + val * sc.y)
                                     : (val * sc.y - pv * sc.x);
                    int d = (odd << 5) + u;
                    dst[((size_t)(b_ * HEADS + hh) * T + t) * 64 + d] = f2bf(outv * scale);
                }
            }
        }
    } else {
#pragma unroll
        for (int i = 0; i < 2; ++i) {
            int mrow0 = bm + wr * 32 + i * 16 + l4 * 4;
            int b_ = mrow0 >> 12, t = mrow0 & 4095;
#pragma unroll
            for (int j = 0; j < 4; ++j) {
                int n = bn + wc * 64 + j * 16 + l15;
                int hh = n >> 6, dd = n & 63;
                float bb = bias[n];
                uint2v s;
                s.x = pk2bf(acc[i][j][0] + bb, acc[i][j][1] + bb);
                s.y = pk2bf(acc[i][j][2] + bb, acc[i][j][3] + bb);
                *reinterpret_cast<uint2v*>(
                    &dst[((size_t)(b_ * HEADS + hh) * 64 + dd) * TK + t]) = s;
            }
        }
    }
}

// ---------------------------------------------------------------------------
// Output projection GEMM (bf16 in, fp32 out), R10 replay-proven body;
// XCD-pinned 1D grid: 192 = 8 XCDs x (4 bm x 6 bn).
// ---------------------------------------------------------------------------
__global__ __launch_bounds__(256) void gemm_out(const short* __restrict__ Xh,
                                                const float* __restrict__ W,
                                                const float* __restrict__ bias,
                                                float* __restrict__ Y) {
    __shared__ short Alds[128 * 40];
    __shared__ short Blds[128 * 40];
    const int tid = threadIdx.x;
    const int lane = tid & 63, wid = tid >> 6;
    const int wr = wid >> 1, wc = wid & 1;
    const int l4 = lane >> 4, l15 = lane & 15;
    const int id = blockIdx.x;
    const int xcd = id & 7, pos = id >> 3;
    const int bm = (xcd * 4 + pos / 6) * 128;
    const int bn = (pos % 6) * 128;

    int srow[4], skq[4];
#pragma unroll
    for (int p = 0; p < 4; ++p) {
        int c = p * 256 + tid;
        srow[p] = c >> 3; skq[p] = (c & 7) * 4;
    }

    f32x4 acc[4][4] = {};
    short4v ra[4]; float4 fw[4];

#pragma unroll
    for (int p = 0; p < 4; ++p) {
        ra[p] = *reinterpret_cast<const short4v*>(&Xh[(size_t)(bm + srow[p]) * DM + skq[p]]);
        fw[p] = *reinterpret_cast<const float4*>(&W[(size_t)(bn + srow[p]) * DM + skq[p]]);
    }

    for (int k0 = 0; k0 < DM; k0 += 32) {
#pragma unroll
        for (int p = 0; p < 4; ++p) {
            *reinterpret_cast<short4v*>(&Alds[srow[p] * 40 + skq[p]]) = ra[p];
            uint2v t4; t4.x = pk2bf(fw[p].x, fw[p].y); t4.y = pk2bf(fw[p].z, fw[p].w);
            *reinterpret_cast<uint2v*>(&Blds[srow[p] * 40 + skq[p]]) = t4;
        }
        __syncthreads();

        if (k0 + 32 < DM) {
#pragma unroll
            for (int p = 0; p < 4; ++p) {
                ra[p] = *reinterpret_cast<const short4v*>(&Xh[(size_t)(bm + srow[p]) * DM + k0 + 32 + skq[p]]);
                fw[p] = *reinterpret_cast<const float4*>(&W[(size_t)(bn + srow[p]) * DM + k0 + 32 + skq[p]]);
            }
        }

        bf16x8 af[4], bfr[4];
#pragma unroll
        for (int i = 0; i < 4; ++i)
            af[i] = *reinterpret_cast<const bf16x8*>(&Alds[(wr * 64 + i * 16 + l15) * 40 + l4 * 8]);
#pragma unroll
        for (int j = 0; j < 4; ++j)
            bfr[j] = *reinterpret_cast<const bf16x8*>(&Blds[(wc * 64 + j * 16 + l15) * 40 + l4 * 8]);
        __builtin_amdgcn_s_setprio(1);
#pragma unroll
        for (int i = 0; i < 4; ++i)
#pragma unroll
            for (int j = 0; j < 4; ++j)
                acc[i][j] = __builtin_amdgcn_mfma_f32_16x16x32_bf16(af[i], bfr[j], acc[i][j], 0, 0, 0);
        __builtin_amdgcn_s_setprio(0);
        __syncthreads();
    }

#pragma unroll
    for (int i = 0; i < 4; ++i) {
        int m = bm + wr * 64 + i * 16 + l4 * 4;
#pragma unroll
        for (int j = 0; j < 4; ++j) {
            int n = bn + wc * 64 + j * 16 + l15;
            float bb = bias[n];
#pragma unroll
            for (int r = 0; r < 4; ++r)
                Y[(size_t)(m + r) * DM + n] = acc[i][j][r] + bb;
        }
    }
}

// ---------------------------------------------------------------------------
// Flash attention, NO-MAX softmax (R12 replay-proven, unchanged).
// ---------------------------------------------------------------------------
__global__ __launch_bounds__(256, 4) void attn(const short* __restrict__ qh,
                                               const short* __restrict__ kh,
                                               const short* __restrict__ vt,
                                               short* __restrict__ Opart,
                                               float* __restrict__ ml) {
    __shared__ short Ks[2][64 * 64];
    __shared__ short Vs[2][64 * 64];
    const int id = blockIdx.x;
    const int hs = id % 96, qt = id / 96;
    const int h = hs % HEADS, rest = hs / HEADS;
    const int split = rest & 3, b = rest >> 2;
    const int tid = threadIdx.x, lane = tid & 63, w = tid >> 6;
    const int l31 = lane & 31, hi = lane >> 5;
    const size_t bh = (size_t)(b * HEADS + h);
    const short* kbase = kh + bh * TK * 64;
    const short* vbase = vt + bh * (size_t)64 * TK;
    const int t0 = split * KTS;

#define SWZ(row, bo) ((row) * 64 + ((((bo)) ^ (((row) & 7) << 4)) >> 1))
#define KGLB(c, t_) (kbase + ((size_t)(t_) * 64 + ((c) >> 3)) * 64 + ((c) & 7) * 8)
#define VGLB(c, t_) (vbase + (size_t)((c) >> 3) * TK + (t_) * 64 + ((c) & 7) * 8)

    int loff[2][4];
#pragma unroll
    for (int t2 = 0; t2 < 2; ++t2)
#pragma unroll
        for (int d0 = 0; d0 < 4; ++d0)
            loff[t2][d0] = SWZ(t2 * 32 + l31, d0 * 32 + hi * 16);

    bf16x8 qf[4];
    {
        const short* qrow = qh + (bh * TQ + (size_t)qt * 128 + w * 32 + l31) * 64 + hi * 8;
#pragma unroll
        for (int d0 = 0; d0 < 4; ++d0)
            qf[d0] = *reinterpret_cast<const bf16x8*>(qrow + d0 * 16);
    }

    f32x16 oacc[2] = {};
    float lsum = 0.f;

    const int c0 = tid, c1 = tid + 256;
    const int sw0 = SWZ(c0 >> 3, (c0 & 7) * 16), sw1 = SWZ(c1 >> 3, (c1 & 7) * 16);

    {
        bf16x8 k0 = *reinterpret_cast<const bf16x8*>(KGLB(c0, t0));
        bf16x8 k1 = *reinterpret_cast<const bf16x8*>(KGLB(c1, t0));
        bf16x8 v0 = *reinterpret_cast<const bf16x8*>(VGLB(c0, t0));
        bf16x8 v1 = *reinterpret_cast<const bf16x8*>(VGLB(c1, t0));
        *reinterpret_cast<bf16x8*>(&Ks[0][sw0]) = k0;
        *reinterpret_cast<bf16x8*>(&Ks[0][sw1]) = k1;
        *reinterpret_cast<bf16x8*>(&Vs[0][sw0]) = v0;
        *reinterpret_cast<bf16x8*>(&Vs[0][sw1]) = v1;
    }
    __syncthreads();

    int cur = 0;
    for (int kt = 0; kt < KTS; ++kt) {
        const bool pre = (kt + 1 < KTS);
        bf16x8 sk0, sk1, sv0, sv1;
        if (pre) {
            sk0 = *reinterpret_cast<const bf16x8*>(KGLB(c0, t0 + kt + 1));
            sk1 = *reinterpret_cast<const bf16x8*>(KGLB(c1, t0 + kt + 1));
            sv0 = *reinterpret_cast<const bf16x8*>(VGLB(c0, t0 + kt + 1));
            sv1 = *reinterpret_cast<const bf16x8*>(VGLB(c1, t0 + kt + 1));
        }

        // ---- QK^T ----
        f32x16 sacc[2] = {};
        __builtin_amdgcn_s_setprio(1);
#pragma unroll
        for (int t2 = 0; t2 < 2; ++t2)
#pragma unroll
            for (int d0 = 0; d0 < 4; ++d0) {
                bf16x8 kf = *reinterpret_cast<const bf16x8*>(&Ks[cur][loff[t2][d0]]);
                sacc[t2] = __builtin_amdgcn_mfma_f32_32x32x16_bf16(kf, qf[d0], sacc[t2], 0, 0, 0);
            }
        __builtin_amdgcn_s_setprio(0);

        // ---- P = exp2(S) directly + tree sum ----
#pragma unroll
        for (int t2 = 0; t2 < 2; ++t2)
#pragma unroll
            for (int i = 0; i < 16; ++i)
                sacc[t2][i] = exp2f(sacc[t2][i]);
        float s8[8];
#pragma unroll
        for (int i = 0; i < 8; ++i)
            s8[i] = (sacc[0][i] + sacc[0][i + 8]) + (sacc[1][i] + sacc[1][i + 8]);
        float rs = ((s8[0] + s8[1]) + (s8[2] + s8[3])) + ((s8[4] + s8[5]) + (s8[6] + s8[7]));
        {
            unsigned a, bb2;
            plswap2(a, bb2, __float_as_uint(rs));
            rs = __uint_as_float(a) + __uint_as_float(bb2);
        }
        lsum += rs;

        // ---- P -> PV fragments: cvt_pk + permlane32_swap ----
#define PP(idx) (sacc[(idx) >> 4][(idx) & 15])
        bf16x8 pa[4];
#pragma unroll
        for (int ks = 0; ks < 4; ++ks) {
            const int base = (ks >> 1) * 16 + (ks & 1) * 8;
            unsigned u0 = pk2bf(PP(base + 0), PP(base + 1));
            unsigned u1 = pk2bf(PP(base + 2), PP(base + 3));
            unsigned u2 = pk2bf(PP(base + 4), PP(base + 5));
            unsigned u3 = pk2bf(PP(base + 6), PP(base + 7));
            plswap(u0, u2);
            plswap(u1, u3);
            union { unsigned u[4]; bf16x8 v; } asm_;
            asm_.u[0] = u0; asm_.u[1] = u1; asm_.u[2] = u2; asm_.u[3] = u3;
            pa[ks] = asm_.v;
        }
#undef PP

        // ---- write next tile to other buffer ----
        if (pre) {
            *reinterpret_cast<bf16x8*>(&Ks[cur ^ 1][sw0]) = sk0;
            *reinterpret_cast<bf16x8*>(&Ks[cur ^ 1][sw1]) = sk1;
            *reinterpret_cast<bf16x8*>(&Vs[cur ^ 1][sw0]) = sv0;
            *reinterpret_cast<bf16x8*>(&Vs[cur ^ 1][sw1]) = sv1;
        }

        // ---- PV: O^T[d,q] += V^T x P^T ----
        __builtin_amdgcn_s_setprio(1);
#pragma unroll
        for (int dt = 0; dt < 2; ++dt)
#pragma unroll
            for (int ks = 0; ks < 4; ++ks) {
                bf16x8 vf = *reinterpret_cast<const bf16x8*>(&Vs[cur][loff[dt][ks]]);
                oacc[dt] = __builtin_amdgcn_mfma_f32_32x32x16_bf16(vf, pa[ks], oacc[dt], 0, 0, 0);
            }
        __builtin_amdgcn_s_setprio(0);

        __syncthreads();
        cur ^= 1;
    }

    float rln = 1.f / lsum;
    const size_t R = bh * TQ + (size_t)qt * 128 + w * 32 + l31;
    const size_t obase = ((size_t)split * ROWS + R) * 64;
#pragma unroll
    for (int dt = 0; dt < 2; ++dt)
#pragma unroll
        for (int rq = 0; rq < 4; ++rq) {
            uint2v st;
            st.x = pk2bf(oacc[dt][rq * 4 + 0] * rln, oacc[dt][rq * 4 + 1] * rln);
            st.y = pk2bf(oacc[dt][rq * 4 + 2] * rln, oacc[dt][rq * 4 + 3] * rln);
            *reinterpret_cast<uint2v*>(&Opart[obase + dt * 32 + rq * 8 + hi * 4]) = st;
        }
    if (hi == 0)
        ml[(size_t)split * ROWS + R] = lsum;
#undef SWZ
#undef KGLB
#undef VGLB
}

// ---------------------------------------------------------------------------
// Combine NSPLIT partials: weighted average with weights lsum_s / sum(lsum_s).
// ---------------------------------------------------------------------------
__global__ __launch_bounds__(256) void attn_combine(const short* __restrict__ Opart,
                                                    const float* __restrict__ ml,
                                                    short* __restrict__ attnO) {
    int idx = blockIdx.x * 256 + threadIdx.x;
    int R = idx >> 3, g = idx & 7;
    float wgt[NSPLIT], L = 0.f;
#pragma unroll
    for (int s = 0; s < NSPLIT; ++s) {
        wgt[s] = ml[(size_t)s * ROWS + R];
        L += wgt[s];
    }
    float rL = 1.f / L;
    float o[8] = {};
#pragma unroll
    for (int s = 0; s < NSPLIT; ++s) {
        float c = wgt[s] * rL;
        bf16x8 v = *reinterpret_cast<const bf16x8*>(&Opart[(((size_t)s * ROWS + R) * 64) + g * 8]);
#pragma unroll
        for (int i = 0; i < 8; ++i) o[i] += c * bf2f(v[i]);
    }
    int bh = R >> 11, t = R & 2047;
    int b = bh / HEADS, h = bh - b * HEADS;
    uint2v s0, s1;
    s0.x = pk2bf(o[0], o[1]); s0.y = pk2bf(o[2], o[3]);
    s1.x = pk2bf(o[4], o[5]); s1.y = pk2bf(o[6], o[7]);
    size_t dst = (((size_t)b * TQ + t) * HEADS + h) * 64 + g * 8;
    *reinterpret_cast<uint2v*>(&attnO[dst]) = s0;
    *reinterpret_cast<uint2v*>(&attnO[dst + 4]) = s1;
}

// ---------------------------------------------------------------------------
extern "C" void kernel_launch(void* const* d_in, const int* in_sizes, int n_in,
                              void* d_out, int out_size, void* d_ws, size_t ws_size,
                              hipStream_t stream) {
    const float* query = (const float*)d_in[0];
    const float* key_  = (const float*)d_in[1];
    const float* value = (const float*)d_in[2];
    const float* Wq = (const float*)d_in[3];
    const float* bq = (const float*)d_in[4];
    const float* Wk = (const float*)d_in[5];
    const float* bk = (const float*)d_in[6];
    const float* Wv = (const float*)d_in[7];
    const float* bv = (const float*)d_in[8];
    const float* Wo = (const float*)d_in[9];
    const float* bo = (const float*)d_in[10];
    float* out = (float*)d_out;

    char* ws = (char*)d_ws;
    float2* scu  = (float2*)(ws + 0);           // 1,048,576 B
    short* qh    = (short*)(ws + 1048576);      // 6,291,456 B
    short* kh    = (short*)(ws + 7340032);      // 12,582,912 B
    short* vt    = (short*)(ws + 19922944);     // 12,582,912 B
    short* attnO = (short*)(ws + 32505856);     // 6,291,456 B
    short* Opart = (short*)(ws + 38797312);     // 25,165,824 B
    float* ml    = (float*)(ws + 63963136);     //   786,432 B (end ~64.7 MB)

    dim3 blk(256);
    const float QSCALE = 0.125f * 1.44269504088896341f;   // 1/sqrt(64) * log2(e)

    rope_tables<<<(TK * 32 + 255) / 256, blk, 0, stream>>>(scu);
    // fused Q/K/V projection + RoPE/transpose, XCD-pinned (1920 blocks),
    // A via global_load_lds DMA (swizzled source)
    gemm_qkv<<<dim3(1920), blk, 0, stream>>>(query, key_, value, Wq, bq, Wk, bk,
                                             Wv, bv, scu, qh, kh, vt, QSCALE);
    // attention: 4-wave / 128-row blocks, swizzled 1D grid (1536 blocks)
    attn<<<dim3(16 * 96), blk, 0, stream>>>(qh, kh, vt, Opart, ml);
    attn_combine<<<ROWS * 8 / 256, blk, 0, stream>>>(Opart, ml, attnO);
    // output projection, XCD-pinned 1D grid (192 blocks)
    gemm_out<<<dim3(192), blk, 0, stream>>>(attnO, Wo, bo, out);
}

// Round 20
// 186.740 us; speedup vs baseline: 1.0689x; 1.0689x over previous
//
#include <hip/hip_runtime.h>
#include <hip/hip_bf16.h>
#include <math.h>

#define DM 768
#define HEADS 12
#define BQ 2
#define TQ 2048
#define TK 4096
#define NSPLIT 4
#define KTS (TK / 64 / NSPLIT)          // K-tiles per split = 16
#define ROWS (BQ * HEADS * TQ)          // 49152 q-rows total

typedef __attribute__((ext_vector_type(8))) short bf16x8;   // 8 bf16 (4 VGPRs) MFMA frag
typedef __attribute__((ext_vector_type(4))) float f32x4;    // 16x16 MFMA accum
typedef __attribute__((ext_vector_type(16))) float f32x16;  // 32x32 MFMA accum
typedef __attribute__((ext_vector_type(4))) short short4v;  // 8B vector
typedef __attribute__((ext_vector_type(2))) unsigned uint2v; // 8B vector

// packed 2x f32 -> 1x u32 (2 bf16, lo = first arg); v_cvt_pk_bf16_f32
__device__ inline unsigned pk2bf(float a, float b) {
    union { __hip_bfloat162 h; unsigned u; } c;
    c.h = __float22bfloat162_rn(make_float2(a, b));
    return c.u;
}
// single f32->bf16 RNE in ONE instruction (cvt_pk with dup, take low half)
__device__ inline short f2bf(float f) { return (short)(pk2bf(f, f) & 0xffffu); }

__device__ inline float bf2f(short s) {
    union { unsigned u; float f; } a; a.u = ((unsigned)(unsigned short)s) << 16;
    return a.f;
}

// v_permlane32_swap_b32 builtin (compiler owns hazard wait-states).
__device__ inline void plswap(unsigned &a, unsigned &b) {
    uint2v r = __builtin_amdgcn_permlane32_swap(a, b, false, false);
    a = r[0]; b = r[1];
}
__device__ inline void plswap2(unsigned &a, unsigned &b, unsigned x) {
    uint2v r = __builtin_amdgcn_permlane32_swap(x, x, false, false);
    a = r[0]; b = r[1];
}

// ---------------------------------------------------------------------------
// RoPE table, packed float2 {su, cu} per (t, u). fp64 (matches np float64 ref).
// ---------------------------------------------------------------------------
__global__ void rope_tables(float2* scu) {
    int idx = blockIdx.x * 256 + threadIdx.x;
    if (idx >= TK * 32) return;
    int t = idx >> 5, j = idx & 31;
    double su, cu;
    if (j < 16) {
        su = sin((double)t * pow(10000.0, -(double)(2 * (2 * j)) / 64.0));
        cu = sin((double)t * pow(10000.0, -(double)(2 * (2 * j + 1)) / 64.0));
    } else {
        su = cos((double)t * pow(10000.0, -(double)(2 * (2 * j - 32)) / 64.0));
        cu = cos((double)t * pow(10000.0, -(double)(2 * (2 * j - 31)) / 64.0));
    }
    scu[idx] = make_float2((float)su, (float)cu);
}

// ---------------------------------------------------------------------------
// Fused QKV projection + RoPE (Q,K) / transpose (V) epilogue.
// FINAL (R17 config, session best 186.9 us): BK=64, 128x128 tile, XCD-pinned
// 1D grid, 1-deep reg-staged prefetch, plain launch_bounds(256).
// Session evidence: prefetch depth (R9/R10), occupancy (R16), BK (R17),
// tile/TLP (R18), L2 locality (R13-15), global_load_lds DMA (R19) all
// within +-5% — this kernel's remaining gap is instruction-level
// scheduling (guide: hand-asm K-loop territory), out of source-level reach.
// ---------------------------------------------------------------------------
__global__ __launch_bounds__(256) void gemm_qkv(
        const float* __restrict__ query, const float* __restrict__ key_,
        const float* __restrict__ value,
        const float* __restrict__ Wq, const float* __restrict__ bq,
        const float* __restrict__ Wk, const float* __restrict__ bk,
        const float* __restrict__ Wv, const float* __restrict__ bv,
        const float2* __restrict__ scu,
        short* __restrict__ qh, short* __restrict__ kh, short* __restrict__ vt,
        float qscale) {
    __shared__ short Alds[128 * 72];
    __shared__ short Blds[128 * 72];
    const int tid = threadIdx.x;
    const int lane = tid & 63, wid = tid >> 6;
    const int wr = wid >> 1, wc = wid & 1;
    const int l4 = lane >> 4, l15 = lane & 15;
    // XCD-pinned decode: 960 blocks = 8 XCDs x (20 bx x 6 bn)
    const int id = blockIdx.x;
    const int xcd = id & 7, pos = id >> 3;
    const int bx = xcd * 20 + pos / 6;
    const int bn = (pos % 6) * 128;

    const float* X; const float* W; const float* bias;
    short* dst; int bm, tsh, mode; float scale;
    if (bx < 32)      { X = query; W = Wq; bias = bq; dst = qh; bm = bx * 128;        tsh = 11; mode = 0; scale = qscale; }
    else if (bx < 96) { X = key_;  W = Wk; bias = bk; dst = kh; bm = (bx - 32) * 128; tsh = 12; mode = 0; scale = 1.f; }
    else              { X = value; W = Wv; bias = bv; dst = vt; bm = (bx - 96) * 128; tsh = 12; mode = 1; scale = 1.f; }
    const int T = 1 << tsh, tmask = T - 1;

    // staging: 128 rows x 64 cols of f32, 8 chunks (float4) per thread
    int srow[8], skq[8];
#pragma unroll
    for (int p = 0; p < 8; ++p) {
        int c = p * 256 + tid;
        srow[p] = c >> 4; skq[p] = (c & 15) * 4;
    }
    const float* Xb = X + (size_t)bm * DM;
    const float* Wb = W + (size_t)bn * DM;

    f32x4 acc[4][4] = {};
    float4 fa[8], fw[8];

    // prologue: K-step 0 in flight
#pragma unroll
    for (int p = 0; p < 8; ++p) {
        fa[p] = *reinterpret_cast<const float4*>(&Xb[(size_t)srow[p] * DM + skq[p]]);
        fw[p] = *reinterpret_cast<const float4*>(&Wb[(size_t)srow[p] * DM + skq[p]]);
    }

    for (int k0 = 0; k0 < DM; k0 += 64) {
        // write staged regs -> LDS (cvt to bf16 here)
#pragma unroll
        for (int p = 0; p < 8; ++p) {
            uint2v s; s.x = pk2bf(fa[p].x, fa[p].y); s.y = pk2bf(fa[p].z, fa[p].w);
            *reinterpret_cast<uint2v*>(&Alds[srow[p] * 72 + skq[p]]) = s;
            uint2v t4; t4.x = pk2bf(fw[p].x, fw[p].y); t4.y = pk2bf(fw[p].z, fw[p].w);
            *reinterpret_cast<uint2v*>(&Blds[srow[p] * 72 + skq[p]]) = t4;
        }
        __syncthreads();

        // issue next K-step's loads NOW; latency hides under ds_read+MFMA
        if (k0 + 64 < DM) {
#pragma unroll
            for (int p = 0; p < 8; ++p) {
                fa[p] = *reinterpret_cast<const float4*>(&Xb[(size_t)srow[p] * DM + k0 + 64 + skq[p]]);
                fw[p] = *reinterpret_cast<const float4*>(&Wb[(size_t)srow[p] * DM + k0 + 64 + skq[p]]);
            }
        }

        // compute: 2 sub-K of 32 (kk), 16 MFMA each
#pragma unroll
        for (int kk = 0; kk < 2; ++kk) {
            bf16x8 af[4], bfr[4];
#pragma unroll
            for (int i = 0; i < 4; ++i)
                af[i] = *reinterpret_cast<const bf16x8*>(&Alds[(wr * 64 + i * 16 + l15) * 72 + kk * 32 + l4 * 8]);
#pragma unroll
            for (int j = 0; j < 4; ++j)
                bfr[j] = *reinterpret_cast<const bf16x8*>(&Blds[(wc * 64 + j * 16 + l15) * 72 + kk * 32 + l4 * 8]);
            __builtin_amdgcn_s_setprio(1);
#pragma unroll
            for (int i = 0; i < 4; ++i)
#pragma unroll
                for (int j = 0; j < 4; ++j)
                    acc[i][j] = __builtin_amdgcn_mfma_f32_16x16x32_bf16(af[i], bfr[j], acc[i][j], 0, 0, 0);
            __builtin_amdgcn_s_setprio(0);
        }
        __syncthreads();
    }

    if (mode == 0) {
#pragma unroll
        for (int i = 0; i < 4; ++i) {
            int mrow0 = bm + wr * 64 + i * 16 + l4 * 4;
#pragma unroll
            for (int j = 0; j < 4; ++j) {
                int n = bn + wc * 64 + j * 16 + l15;
                int hh = n >> 6, c = n & 63, u = c >> 1, odd = c & 1;
                float bb = bias[n];
#pragma unroll
                for (int r = 0; r < 4; ++r) {
                    float val = acc[i][j][r] + bb;
                    float pv = __shfl_xor(val, 1);
                    int mrow = mrow0 + r;
                    int b_ = mrow >> tsh, t = mrow & tmask;
                    float2 sc = scu[t * 32 + u];
                    float outv = odd ? (pv * sc.x + val * sc.y)
                                     : (val * sc.y - pv * sc.x);
                    int d = (odd << 5) + u;
                    dst[((size_t)(b_ * HEADS + hh) * T + t) * 64 + d] = f2bf(outv * scale);
                }
            }
        }
    } else {
#pragma unroll
        for (int i = 0; i < 4; ++i) {
            int mrow0 = bm + wr * 64 + i * 16 + l4 * 4;
            int b_ = mrow0 >> 12, t = mrow0 & 4095;
#pragma unroll
            for (int j = 0; j < 4; ++j) {
                int n = bn + wc * 64 + j * 16 + l15;
                int hh = n >> 6, dd = n & 63;
                float bb = bias[n];
                uint2v s;
                s.x = pk2bf(acc[i][j][0] + bb, acc[i][j][1] + bb);
                s.y = pk2bf(acc[i][j][2] + bb, acc[i][j][3] + bb);
                *reinterpret_cast<uint2v*>(
                    &dst[((size_t)(b_ * HEADS + hh) * 64 + dd) * TK + t]) = s;
            }
        }
    }
}

// ---------------------------------------------------------------------------
// Output projection GEMM (bf16 in, fp32 out), R10 replay-proven body;
// XCD-pinned 1D grid: 192 = 8 XCDs x (4 bm x 6 bn).
// ---------------------------------------------------------------------------
__global__ __launch_bounds__(256) void gemm_out(const short* __restrict__ Xh,
                                                const float* __restrict__ W,
                                                const float* __restrict__ bias,
                                                float* __restrict__ Y) {
    __shared__ short Alds[128 * 40];
    __shared__ short Blds[128 * 40];
    const int tid = threadIdx.x;
    const int lane = tid & 63, wid = tid >> 6;
    const int wr = wid >> 1, wc = wid & 1;
    const int l4 = lane >> 4, l15 = lane & 15;
    const int id = blockIdx.x;
    const int xcd = id & 7, pos = id >> 3;
    const int bm = (xcd * 4 + pos / 6) * 128;
    const int bn = (pos % 6) * 128;

    int srow[4], skq[4];
#pragma unroll
    for (int p = 0; p < 4; ++p) {
        int c = p * 256 + tid;
        srow[p] = c >> 3; skq[p] = (c & 7) * 4;
    }

    f32x4 acc[4][4] = {};
    short4v ra[4]; float4 fw[4];

#pragma unroll
    for (int p = 0; p < 4; ++p) {
        ra[p] = *reinterpret_cast<const short4v*>(&Xh[(size_t)(bm + srow[p]) * DM + skq[p]]);
        fw[p] = *reinterpret_cast<const float4*>(&W[(size_t)(bn + srow[p]) * DM + skq[p]]);
    }

    for (int k0 = 0; k0 < DM; k0 += 32) {
#pragma unroll
        for (int p = 0; p < 4; ++p) {
            *reinterpret_cast<short4v*>(&Alds[srow[p] * 40 + skq[p]]) = ra[p];
            uint2v t4; t4.x = pk2bf(fw[p].x, fw[p].y); t4.y = pk2bf(fw[p].z, fw[p].w);
            *reinterpret_cast<uint2v*>(&Blds[srow[p] * 40 + skq[p]]) = t4;
        }
        __syncthreads();

        if (k0 + 32 < DM) {
#pragma unroll
            for (int p = 0; p < 4; ++p) {
                ra[p] = *reinterpret_cast<const short4v*>(&Xh[(size_t)(bm + srow[p]) * DM + k0 + 32 + skq[p]]);
                fw[p] = *reinterpret_cast<const float4*>(&W[(size_t)(bn + srow[p]) * DM + k0 + 32 + skq[p]]);
            }
        }

        bf16x8 af[4], bfr[4];
#pragma unroll
        for (int i = 0; i < 4; ++i)
            af[i] = *reinterpret_cast<const bf16x8*>(&Alds[(wr * 64 + i * 16 + l15) * 40 + l4 * 8]);
#pragma unroll
        for (int j = 0; j < 4; ++j)
            bfr[j] = *reinterpret_cast<const bf16x8*>(&Blds[(wc * 64 + j * 16 + l15) * 40 + l4 * 8]);
        __builtin_amdgcn_s_setprio(1);
#pragma unroll
        for (int i = 0; i < 4; ++i)
#pragma unroll
            for (int j = 0; j < 4; ++j)
                acc[i][j] = __builtin_amdgcn_mfma_f32_16x16x32_bf16(af[i], bfr[j], acc[i][j], 0, 0, 0);
        __builtin_amdgcn_s_setprio(0);
        __syncthreads();
    }

#pragma unroll
    for (int i = 0; i < 4; ++i) {
        int m = bm + wr * 64 + i * 16 + l4 * 4;
#pragma unroll
        for (int j = 0; j < 4; ++j) {
            int n = bn + wc * 64 + j * 16 + l15;
            float bb = bias[n];
#pragma unroll
            for (int r = 0; r < 4; ++r)
                Y[(size_t)(m + r) * DM + n] = acc[i][j][r] + bb;
        }
    }
}

// ---------------------------------------------------------------------------
// Flash attention, NO-MAX softmax (R12 replay-proven, unchanged).
// ---------------------------------------------------------------------------
__global__ __launch_bounds__(256, 4) void attn(const short* __restrict__ qh,
                                               const short* __restrict__ kh,
                                               const short* __restrict__ vt,
                                               short* __restrict__ Opart,
                                               float* __restrict__ ml) {
    __shared__ short Ks[2][64 * 64];
    __shared__ short Vs[2][64 * 64];
    const int id = blockIdx.x;
    const int hs = id % 96, qt = id / 96;
    const int h = hs % HEADS, rest = hs / HEADS;
    const int split = rest & 3, b = rest >> 2;
    const int tid = threadIdx.x, lane = tid & 63, w = tid >> 6;
    const int l31 = lane & 31, hi = lane >> 5;
    const size_t bh = (size_t)(b * HEADS + h);
    const short* kbase = kh + bh * TK * 64;
    const short* vbase = vt + bh * (size_t)64 * TK;
    const int t0 = split * KTS;

#define SWZ(row, bo) ((row) * 64 + ((((bo)) ^ (((row) & 7) << 4)) >> 1))
#define KGLB(c, t_) (kbase + ((size_t)(t_) * 64 + ((c) >> 3)) * 64 + ((c) & 7) * 8)
#define VGLB(c, t_) (vbase + (size_t)((c) >> 3) * TK + (t_) * 64 + ((c) & 7) * 8)

    int loff[2][4];
#pragma unroll
    for (int t2 = 0; t2 < 2; ++t2)
#pragma unroll
        for (int d0 = 0; d0 < 4; ++d0)
            loff[t2][d0] = SWZ(t2 * 32 + l31, d0 * 32 + hi * 16);

    bf16x8 qf[4];
    {
        const short* qrow = qh + (bh * TQ + (size_t)qt * 128 + w * 32 + l31) * 64 + hi * 8;
#pragma unroll
        for (int d0 = 0; d0 < 4; ++d0)
            qf[d0] = *reinterpret_cast<const bf16x8*>(qrow + d0 * 16);
    }

    f32x16 oacc[2] = {};
    float lsum = 0.f;

    const int c0 = tid, c1 = tid + 256;
    const int sw0 = SWZ(c0 >> 3, (c0 & 7) * 16), sw1 = SWZ(c1 >> 3, (c1 & 7) * 16);

    {
        bf16x8 k0 = *reinterpret_cast<const bf16x8*>(KGLB(c0, t0));
        bf16x8 k1 = *reinterpret_cast<const bf16x8*>(KGLB(c1, t0));
        bf16x8 v0 = *reinterpret_cast<const bf16x8*>(VGLB(c0, t0));
        bf16x8 v1 = *reinterpret_cast<const bf16x8*>(VGLB(c1, t0));
        *reinterpret_cast<bf16x8*>(&Ks[0][sw0]) = k0;
        *reinterpret_cast<bf16x8*>(&Ks[0][sw1]) = k1;
        *reinterpret_cast<bf16x8*>(&Vs[0][sw0]) = v0;
        *reinterpret_cast<bf16x8*>(&Vs[0][sw1]) = v1;
    }
    __syncthreads();

    int cur = 0;
    for (int kt = 0; kt < KTS; ++kt) {
        const bool pre = (kt + 1 < KTS);
        bf16x8 sk0, sk1, sv0, sv1;
        if (pre) {
            sk0 = *reinterpret_cast<const bf16x8*>(KGLB(c0, t0 + kt + 1));
            sk1 = *reinterpret_cast<const bf16x8*>(KGLB(c1, t0 + kt + 1));
            sv0 = *reinterpret_cast<const bf16x8*>(VGLB(c0, t0 + kt + 1));
            sv1 = *reinterpret_cast<const bf16x8*>(VGLB(c1, t0 + kt + 1));
        }

        // ---- QK^T ----
        f32x16 sacc[2] = {};
        __builtin_amdgcn_s_setprio(1);
#pragma unroll
        for (int t2 = 0; t2 < 2; ++t2)
#pragma unroll
            for (int d0 = 0; d0 < 4; ++d0) {
                bf16x8 kf = *reinterpret_cast<const bf16x8*>(&Ks[cur][loff[t2][d0]]);
                sacc[t2] = __builtin_amdgcn_mfma_f32_32x32x16_bf16(kf, qf[d0], sacc[t2], 0, 0, 0);
            }
        __builtin_amdgcn_s_setprio(0);

        // ---- P = exp2(S) directly + tree sum ----
#pragma unroll
        for (int t2 = 0; t2 < 2; ++t2)
#pragma unroll
            for (int i = 0; i < 16; ++i)
                sacc[t2][i] = exp2f(sacc[t2][i]);
        float s8[8];
#pragma unroll
        for (int i = 0; i < 8; ++i)
            s8[i] = (sacc[0][i] + sacc[0][i + 8]) + (sacc[1][i] + sacc[1][i + 8]);
        float rs = ((s8[0] + s8[1]) + (s8[2] + s8[3])) + ((s8[4] + s8[5]) + (s8[6] + s8[7]));
        {
            unsigned a, bb2;
            plswap2(a, bb2, __float_as_uint(rs));
            rs = __uint_as_float(a) + __uint_as_float(bb2);
        }
        lsum += rs;

        // ---- P -> PV fragments: cvt_pk + permlane32_swap ----
#define PP(idx) (sacc[(idx) >> 4][(idx) & 15])
        bf16x8 pa[4];
#pragma unroll
        for (int ks = 0; ks < 4; ++ks) {
            const int base = (ks >> 1) * 16 + (ks & 1) * 8;
            unsigned u0 = pk2bf(PP(base + 0), PP(base + 1));
            unsigned u1 = pk2bf(PP(base + 2), PP(base + 3));
            unsigned u2 = pk2bf(PP(base + 4), PP(base + 5));
            unsigned u3 = pk2bf(PP(base + 6), PP(base + 7));
            plswap(u0, u2);
            plswap(u1, u3);
            union { unsigned u[4]; bf16x8 v; } asm_;
            asm_.u[0] = u0; asm_.u[1] = u1; asm_.u[2] = u2; asm_.u[3] = u3;
            pa[ks] = asm_.v;
        }
#undef PP

        // ---- write next tile to other buffer ----
        if (pre) {
            *reinterpret_cast<bf16x8*>(&Ks[cur ^ 1][sw0]) = sk0;
            *reinterpret_cast<bf16x8*>(&Ks[cur ^ 1][sw1]) = sk1;
            *reinterpret_cast<bf16x8*>(&Vs[cur ^ 1][sw0]) = sv0;
            *reinterpret_cast<bf16x8*>(&Vs[cur ^ 1][sw1]) = sv1;
        }

        // ---- PV: O^T[d,q] += V^T x P^T ----
        __builtin_amdgcn_s_setprio(1);
#pragma unroll
        for (int dt = 0; dt < 2; ++dt)
#pragma unroll
            for (int ks = 0; ks < 4; ++ks) {
                bf16x8 vf = *reinterpret_cast<const bf16x8*>(&Vs[cur][loff[dt][ks]]);
                oacc[dt] = __builtin_amdgcn_mfma_f32_32x32x16_bf16(vf, pa[ks], oacc[dt], 0, 0, 0);
            }
        __builtin_amdgcn_s_setprio(0);

        __syncthreads();
        cur ^= 1;
    }

    float rln = 1.f / lsum;
    const size_t R = bh * TQ + (size_t)qt * 128 + w * 32 + l31;
    const size_t obase = ((size_t)split * ROWS + R) * 64;
#pragma unroll
    for (int dt = 0; dt < 2; ++dt)
#pragma unroll
        for (int rq = 0; rq < 4; ++rq) {
            uint2v st;
            st.x = pk2bf(oacc[dt][rq * 4 + 0] * rln, oacc[dt][rq * 4 + 1] * rln);
            st.y = pk2bf(oacc[dt][rq * 4 + 2] * rln, oacc[dt][rq * 4 + 3] * rln);
            *reinterpret_cast<uint2v*>(&Opart[obase + dt * 32 + rq * 8 + hi * 4]) = st;
        }
    if (hi == 0)
        ml[(size_t)split * ROWS + R] = lsum;
#undef SWZ
#undef KGLB
#undef VGLB
}

// ---------------------------------------------------------------------------
// Combine NSPLIT partials: weighted average with weights lsum_s / sum(lsum_s).
// ---------------------------------------------------------------------------
__global__ __launch_bounds__(256) void attn_combine(const short* __restrict__ Opart,
                                                    const float* __restrict__ ml,
                                                    short* __restrict__ attnO) {
    int idx = blockIdx.x * 256 + threadIdx.x;
    int R = idx >> 3, g = idx & 7;
    float wgt[NSPLIT], L = 0.f;
#pragma unroll
    for (int s = 0; s < NSPLIT; ++s) {
        wgt[s] = ml[(size_t)s * ROWS + R];
        L += wgt[s];
    }
    float rL = 1.f / L;
    float o[8] = {};
#pragma unroll
    for (int s = 0; s < NSPLIT; ++s) {
        float c = wgt[s] * rL;
        bf16x8 v = *reinterpret_cast<const bf16x8*>(&Opart[(((size_t)s * ROWS + R) * 64) + g * 8]);
#pragma unroll
        for (int i = 0; i < 8; ++i) o[i] += c * bf2f(v[i]);
    }
    int bh = R >> 11, t = R & 2047;
    int b = bh / HEADS, h = bh - b * HEADS;
    uint2v s0, s1;
    s0.x = pk2bf(o[0], o[1]); s0.y = pk2bf(o[2], o[3]);
    s1.x = pk2bf(o[4], o[5]); s1.y = pk2bf(o[6], o[7]);
    size_t dst = (((size_t)b * TQ + t) * HEADS + h) * 64 + g * 8;
    *reinterpret_cast<uint2v*>(&attnO[dst]) = s0;
    *reinterpret_cast<uint2v*>(&attnO[dst + 4]) = s1;
}

// ---------------------------------------------------------------------------
extern "C" void kernel_launch(void* const* d_in, const int* in_sizes, int n_in,
                              void* d_out, int out_size, void* d_ws, size_t ws_size,
                              hipStream_t stream) {
    const float* query = (const float*)d_in[0];
    const float* key_  = (const float*)d_in[1];
    const float* value = (const float*)d_in[2];
    const float* Wq = (const float*)d_in[3];
    const float* bq = (const float*)d_in[4];
    const float* Wk = (const float*)d_in[5];
    const float* bk = (const float*)d_in[6];
    const float* Wv = (const float*)d_in[7];
    const float* bv = (const float*)d_in[8];
    const float* Wo = (const float*)d_in[9];
    const float* bo = (const float*)d_in[10];
    float* out = (float*)d_out;

    char* ws = (char*)d_ws;
    float2* scu  = (float2*)(ws + 0);           // 1,048,576 B
    short* qh    = (short*)(ws + 1048576);      // 6,291,456 B
    short* kh    = (short*)(ws + 7340032);      // 12,582,912 B
    short* vt    = (short*)(ws + 19922944);     // 12,582,912 B
    short* attnO = (short*)(ws + 32505856);     // 6,291,456 B
    short* Opart = (short*)(ws + 38797312);     // 25,165,824 B
    float* ml    = (float*)(ws + 63963136);     //   786,432 B (end ~64.7 MB)

    dim3 blk(256);
    const float QSCALE = 0.125f * 1.44269504088896341f;   // 1/sqrt(64) * log2(e)

    rope_tables<<<(TK * 32 + 255) / 256, blk, 0, stream>>>(scu);
    // fused Q/K/V projection + RoPE/transpose, XCD-pinned 1D grid (960 blocks), BK=64
    gemm_qkv<<<dim3(960), blk, 0, stream>>>(query, key_, value, Wq, bq, Wk, bk,
                                            Wv, bv, scu, qh, kh, vt, QSCALE);
    // attention: 4-wave / 128-row blocks, swizzled 1D grid (1536 blocks)
    attn<<<dim3(16 * 96), blk, 0, stream>>>(qh, kh, vt, Opart, ml);
    attn_combine<<<ROWS * 8 / 256, blk, 0, stream>>>(Opart, ml, attnO);
    // output projection, XCD-pinned 1D grid (192 blocks)
    gemm_out<<<dim3(192), blk, 0, stream>>>(attnO, Wo, bo, out);
}